// Round 6
// baseline (484.120 us; speedup 1.0000x reference)
//
#include <hip/hip_runtime.h>

// CRF forward: B=256, T<=2048, C=64. ONE WAVE per batch. Zero LDS, zero barriers.
// Recurrence in linear space with deferred uniform renorm:
//   S_t = E . q_{t-1}   (E = exp(trans), bf16, via 4 row-tiles x 2 K-chunks of
//                        mfma_f32_16x16x32_bf16; 8 MFMAs, chain depth 2)
//   q_t = exp2(x_t*log2e - delta_t) * S_t,  delta_t = log2(firstlane(S_{t-1}[0]))
//   Mbar += delta_t (exact shift bookkeeping);  alpha = ln2*(Mbar + log2 q)
// Layout trick: with k-bijection kappa(g,i) = 4g + (i&3) + 16*(i>>2) used for BOTH
// A(=E, loaded once) and B(=q), the D rows each lane holds (16mt+4g+reg; verified
// C/D layout) are exactly the B-slots its next fragment needs -> q recirculates
// lane-locally: 16 v_mul + 8 v_cvt_pk per step. Same cvt_pk packs E and q, so
// lo/hi pairing is consistent by construction.

#define CC 64
#define PF 4

typedef short bf16x8 __attribute__((ext_vector_type(8)));
typedef float f32x4 __attribute__((ext_vector_type(4)));

union PackAB { int w[4]; bf16x8 v; };

__device__ __forceinline__ int cvtpk(float lo, float hi) {
    int r;
    asm("v_cvt_pk_bf16_f32 %0, %1, %2" : "=v"(r) : "v"(lo), "v"(hi));
    return r;
}
__device__ __forceinline__ float bcast0(float v) {
    return __int_as_float(__builtin_amdgcn_readfirstlane(__float_as_int(v)));
}
// verified (round 5): sum of both permlane*_swap outputs == v[l] + v[l^G]
__device__ __forceinline__ float pairsum16(float v) {
#if __has_builtin(__builtin_amdgcn_permlane16_swap)
    unsigned u = __float_as_uint(v);
    auto r = __builtin_amdgcn_permlane16_swap(u, u, false, false);
    return __uint_as_float(r[0]) + __uint_as_float(r[1]);
#else
    return v + __int_as_float(__builtin_amdgcn_ds_swizzle(__float_as_int(v), 0x401F));
#endif
}
__device__ __forceinline__ float pairsum32(float v, int lane) {
#if __has_builtin(__builtin_amdgcn_permlane32_swap)
    unsigned u = __float_as_uint(v);
    auto r = __builtin_amdgcn_permlane32_swap(u, u, false, false);
    return __uint_as_float(r[0]) + __uint_as_float(r[1]);
#else
    int idx = (lane ^ 32) << 2;
    return v + __int_as_float(__builtin_amdgcn_ds_bpermute(idx, __float_as_int(v)));
#endif
}

__launch_bounds__(64, 1)
__global__ void crf_fwd_kernel(const float* __restrict__ x,      // (B,T,C)
                               const float* __restrict__ trans,  // (C,C)
                               const float* __restrict__ orig,   // (C,)
                               const int*   __restrict__ lens,   // (B,)
                               float* __restrict__ out,          // (B,)
                               int T) {
    const int b = blockIdx.x;
    const int l = threadIdx.x;
    const int c = l & 15, g = l >> 4;
    const float L2E = 1.4426950408889634f, LN2 = 0.6931471805599453f;

    // ---- A fragments: A[mt][ch] slot (g,i) holds E[16mt+c][32ch + kappa(g,i)],
    //      kappa(g,i) = 4g + (i&3) + 16*(i>>2)
    bf16x8 A[4][2];
    #pragma unroll
    for (int mt = 0; mt < 4; ++mt) {
        const float* tr = trans + (16 * mt + c) * CC;
        #pragma unroll
        for (int ch = 0; ch < 2; ++ch) {
            float4 u = *(const float4*)(tr + 32 * ch + 4 * g);
            float4 w = *(const float4*)(tr + 32 * ch + 16 + 4 * g);
            PackAB pk;
            pk.w[0] = cvtpk(__builtin_amdgcn_exp2f(u.x * L2E), __builtin_amdgcn_exp2f(u.y * L2E));
            pk.w[1] = cvtpk(__builtin_amdgcn_exp2f(u.z * L2E), __builtin_amdgcn_exp2f(u.w * L2E));
            pk.w[2] = cvtpk(__builtin_amdgcn_exp2f(w.x * L2E), __builtin_amdgcn_exp2f(w.y * L2E));
            pk.w[3] = cvtpk(__builtin_amdgcn_exp2f(w.z * L2E), __builtin_amdgcn_exp2f(w.w * L2E));
            A[mt][ch] = pk.v;
        }
    }

    const int L = lens[b];
    const int Lm1 = L - 1;
    const float* xb = x + (size_t)b * T * CC;

    // ---- init: lane's 16 rows R = 16mt + 4g + reg
    float Mbar;
    float qv[4][4];
    {
        float x00  = xb[0], o0 = orig[0];
        Mbar = (x00 + o0) * L2E;
        #pragma unroll
        for (int mt = 0; mt < 4; ++mt) {
            f32x4 xv = *(const f32x4*)(xb + 16 * mt + 4 * g);
            f32x4 ov = *(const f32x4*)(orig + 16 * mt + 4 * g);
            #pragma unroll
            for (int r = 0; r < 4; ++r)
                qv[mt][r] = __builtin_amdgcn_exp2f((xv[r] + ov[r]) * L2E - Mbar);
        }
    }
    float qk[4][4]; float Mk = Mbar;
    #pragma unroll
    for (int mt = 0; mt < 4; ++mt)
        #pragma unroll
        for (int r = 0; r < 4; ++r) qk[mt][r] = qv[mt][r];

    // ---- B fragments from q (lane-local; same cvt_pk as A)
    PackAB B0, B1;
    #define BUILD_B() do {                                   \
        B0.w[0] = cvtpk(qv[0][0], qv[0][1]);                 \
        B0.w[1] = cvtpk(qv[0][2], qv[0][3]);                 \
        B0.w[2] = cvtpk(qv[1][0], qv[1][1]);                 \
        B0.w[3] = cvtpk(qv[1][2], qv[1][3]);                 \
        B1.w[0] = cvtpk(qv[2][0], qv[2][1]);                 \
        B1.w[1] = cvtpk(qv[2][2], qv[2][3]);                 \
        B1.w[2] = cvtpk(qv[3][0], qv[3][1]);                 \
        B1.w[3] = cvtpk(qv[3][2], qv[3][3]);                 \
    } while (0)
    BUILD_B();

    // ---- x prefetch ring: XP[u][mt] = x[t=..][16mt+4g .. +3]
    f32x4 XP[PF][4];
    #pragma unroll
    for (int u = 0; u < PF; ++u) {
        int tp = 1 + u; if (tp > T - 1) tp = T - 1;
        #pragma unroll
        for (int mt = 0; mt < 4; ++mt)
            XP[u][mt] = *(const f32x4*)(xb + (size_t)tp * CC + 16 * mt + 4 * g);
    }

    float prevS0 = 1.0f;  // delta_1 = log2(1) = 0

    for (int t0 = 1; t0 < L; t0 += PF) {
        #pragma unroll
        for (int u = 0; u < PF; ++u) {
            const int tt = t0 + u;

            f32x4 xv[4];
            #pragma unroll
            for (int mt = 0; mt < 4; ++mt) xv[mt] = XP[u][mt];
            int tp = tt + PF; if (tp > T - 1) tp = T - 1;
            #pragma unroll
            for (int mt = 0; mt < 4; ++mt)
                XP[u][mt] = *(const f32x4*)(xb + (size_t)tp * CC + 16 * mt + 4 * g);

            float delta = __builtin_amdgcn_logf(prevS0);  // log2, wave-uniform
            Mbar += delta;

            // exr = 2^(x*log2e - delta)   (overlaps with MFMAs below)
            float exr[4][4];
            #pragma unroll
            for (int mt = 0; mt < 4; ++mt)
                #pragma unroll
                for (int r = 0; r < 4; ++r)
                    exr[mt][r] = __builtin_amdgcn_exp2f(fmaf(xv[mt][r], L2E, -delta));

            // S = E . q : 4 row-tiles x 2 K-chunks
            f32x4 D[4];
            #pragma unroll
            for (int mt = 0; mt < 4; ++mt) {
                f32x4 z = {0.f, 0.f, 0.f, 0.f};
                z = __builtin_amdgcn_mfma_f32_16x16x32_bf16(A[mt][0], B0.v, z, 0, 0, 0);
                z = __builtin_amdgcn_mfma_f32_16x16x32_bf16(A[mt][1], B1.v, z, 0, 0, 0);
                D[mt] = z;
            }
            prevS0 = bcast0(D[0][0]);  // lane 0 holds row 0 (g=0, reg 0)

            #pragma unroll
            for (int mt = 0; mt < 4; ++mt)
                #pragma unroll
                for (int r = 0; r < 4; ++r)
                    qv[mt][r] = exr[mt][r] * D[mt][r];

            if (tt == Lm1) {  // wave-uniform branch
                #pragma unroll
                for (int mt = 0; mt < 4; ++mt)
                    #pragma unroll
                    for (int r = 0; r < 4; ++r) qk[mt][r] = qv[mt][r];
                Mk = Mbar;
            }

            BUILD_B();
        }
    }

    // ---- epilogue: alpha = ln2*(Mk + log2 qk); out[b] = sum over 64 rows
    float s = 0.f;
    #pragma unroll
    for (int mt = 0; mt < 4; ++mt)
        #pragma unroll
        for (int r = 0; r < 4; ++r)
            s += LN2 * (Mk + __builtin_amdgcn_logf(qk[mt][r]));
    // rows are partitioned by g (c-lanes hold identical copies): sum over 4 g-groups
    s = pairsum16(s);
    s = pairsum32(s, l);
    if (l == 0) out[b] = s;
}

extern "C" void kernel_launch(void* const* d_in, const int* in_sizes, int n_in,
                              void* d_out, int out_size, void* d_ws, size_t ws_size,
                              hipStream_t stream) {
    const float* x     = (const float*)d_in[0];
    const float* trans = (const float*)d_in[1];
    const float* orig  = (const float*)d_in[2];
    const int*   lens  = (const int*)d_in[3];
    float* out = (float*)d_out;

    const int B = in_sizes[3];
    const int T = in_sizes[0] / (B * CC);

    crf_fwd_kernel<<<B, CC, 0, stream>>>(x, trans, orig, lens, out, T);
}